// Round 5
// baseline (10272.583 us; speedup 1.0000x reference)
//
#include <hip/hip_runtime.h>
#include <hip/hip_bf16.h>
#include <hip/hip_fp16.h>
#include <stdint.h>
#include <type_traits>

// Problem constants
#define B_ 64
#define T_ 1024
#define I_ 256
#define H_ 512
#define G3_ 1536
#define O_ 256

typedef __attribute__((ext_vector_type(4))) float floatx4;
typedef __attribute__((ext_vector_type(8))) short short8;
typedef __attribute__((ext_vector_type(2))) _Float16 half2v;
typedef __attribute__((ext_vector_type(4))) unsigned int u32x4;

// Raw workgroup barrier: drains LDS only, NOT vmcnt. Keeps HBM/LLC ops
// (out stores, xg prefetch, packet stores) off the per-step critical path.
#define BARX() __asm__ volatile("s_waitcnt lgkmcnt(0)\n\ts_barrier" ::: "memory")

static __device__ __forceinline__ float fdot2f(uint32_t a, uint32_t b, float c) {
#if __has_builtin(__builtin_amdgcn_fdot2)
  return __builtin_amdgcn_fdot2(__builtin_bit_cast(half2v, a),
                                __builtin_bit_cast(half2v, b), c, false);
#else
  __half2 ha = __builtin_bit_cast(__half2, a);
  __half2 hb = __builtin_bit_cast(__half2, b);
  float2 fa = __half22float2(ha), fb = __half22float2(hb);
  return c + fa.x * fb.x + fa.y * fb.y;
#endif
}

static __device__ __forceinline__ float sigmoid_f(float x) {
  float e = __expf(-fabsf(x));
  float a = 1.f / (1.f + e);
  return x >= 0.f ? a : 1.f - a;
}
static __device__ __forceinline__ float tanh_f(float x) {
  float e = __expf(-2.f * fabsf(x));
  float a = (1.f - e) / (1.f + e);
  return x >= 0.f ? a : -a;
}
static __device__ __forceinline__ uint32_t pack_h2(float a, float b) {
  return (uint32_t)__half_as_ushort(__float2half(a)) |
         ((uint32_t)__half_as_ushort(__float2half(b)) << 16);
}
static __device__ __forceinline__ uint32_t pack_bf2(float a, float b) {
  return (uint32_t)__builtin_bit_cast(unsigned short, __float2bfloat16(a)) |
         ((uint32_t)__builtin_bit_cast(unsigned short, __float2bfloat16(b)) << 16);
}

// ---------------------------------------------------------------------------
// init: pack W_hh -> fp16 per-thread 48-dword blocks, combined biases, zero h.
// wpack dword index: ((wc*512 + col*16 + ks)*48 + g*16 + i) + l*393216
//   thread (wc,col,ks) of batch-group WGs owns, for each gate g, the fp16
//   pairs of row g*512 + wc*32 + col, k-dwords [ks*16, ks*16+16).
// Packets need NO init: 0xAAAAAAAA poison never equals a tag (tags <= 1025).
// ---------------------------------------------------------------------------
__global__ void init_kernel(const float* __restrict__ Whh0, const float* __restrict__ Whh1,
                            const float* __restrict__ bih0, const float* __restrict__ bhh0,
                            const float* __restrict__ bih1, const float* __restrict__ bhh1,
                            uint32_t* __restrict__ wpack, float* __restrict__ biasv,
                            uint32_t* __restrict__ hstate) {
  int idx = blockIdx.x * 256 + threadIdx.x;
  if (idx < 786432) {
    int l = idx / 393216, r = idx % 393216;
    int i = r % 16;
    int g = (r / 16) % 3;
    int u = r / 48;
    int ks = u % 16;
    int col = (u / 16) % 32;
    int wc = u / 512;
    const float* W = l ? Whh1 : Whh0;
    int row = g * 512 + wc * 32 + col;
    int k = (ks * 16 + i) * 2;
    uint32_t lo = __half_as_ushort(__float2half(W[(size_t)row * 512 + k]));
    uint32_t hi = __half_as_ushort(__float2half(W[(size_t)row * 512 + k + 1]));
    wpack[idx] = lo | (hi << 16);
  }
  int i2 = idx - 786432;
  if (i2 >= 0 && i2 < 3072) {
    int l = i2 / 1536, n = i2 % 1536;
    const float* bi = l ? bih1 : bih0;
    const float* bh = l ? bhh1 : bhh0;
    biasv[i2] = bi[n] + (n < 1024 ? bh[n] : 0.f);
  }
  int i3 = idx - (786432 + 3072);
  if (i3 >= 0 && i3 < 32768) hstate[i3] = 0u;
}

// ---------------------------------------------------------------------------
// GEMM: C[M,N] = A[M,K] * Bw[N,K]^T + bias, bf16 MFMA 16x16x32. (unchanged)
// ---------------------------------------------------------------------------
template <typename TA, typename TC>
__global__ __launch_bounds__(256, 2) void gemm_bt(
    const TA* __restrict__ A, const float* __restrict__ Bw,
    const float* __restrict__ bias, TC* __restrict__ C,
    int K, int lda, int ldc, int tcshift, int t0, int Ttot) {
  __shared__ unsigned short As[128 * 40];
  __shared__ unsigned short Bs[128 * 40];
  const int tid = threadIdx.x;
  const int bm = blockIdx.x, bn = blockIdx.y;
  const int r = tid >> 1, hf = tid & 1;

  const int m = bm * 128 + r;
  const long arow = (long)(m >> tcshift) * Ttot + t0 + (m & ((1 << tcshift) - 1));
  const TA* ap = A + arow * (long)lda + hf * 16;
  const int n = bn * 128 + r;
  const float* bp = Bw + (long)n * K + hf * 16;

  const int wid = tid >> 6, lane = tid & 63;
  const int wm = (wid >> 1) * 64, wn = (wid & 1) * 64;
  const int m16 = lane & 15, quad = lane >> 4;

  floatx4 acc[4][4];
#pragma unroll
  for (int i = 0; i < 4; ++i)
#pragma unroll
    for (int j = 0; j < 4; ++j) acc[i][j] = 0.f;

  for (int k0 = 0; k0 < K; k0 += 32) {
    unsigned short ta[16], tb[16];
    if constexpr (std::is_same<TA, float>::value) {
      const float4* p = (const float4*)(ap + k0);
#pragma unroll
      for (int q = 0; q < 4; ++q) {
        float4 v = p[q];
        ta[q * 4 + 0] = __builtin_bit_cast(unsigned short, __float2bfloat16(v.x));
        ta[q * 4 + 1] = __builtin_bit_cast(unsigned short, __float2bfloat16(v.y));
        ta[q * 4 + 2] = __builtin_bit_cast(unsigned short, __float2bfloat16(v.z));
        ta[q * 4 + 3] = __builtin_bit_cast(unsigned short, __float2bfloat16(v.w));
      }
    } else {
      const uint4* p = (const uint4*)(ap + k0);
      *(uint4*)&ta[0] = p[0];
      *(uint4*)&ta[8] = p[1];
    }
    {
      const float4* p = (const float4*)(bp + k0);
#pragma unroll
      for (int q = 0; q < 4; ++q) {
        float4 v = p[q];
        tb[q * 4 + 0] = __builtin_bit_cast(unsigned short, __float2bfloat16(v.x));
        tb[q * 4 + 1] = __builtin_bit_cast(unsigned short, __float2bfloat16(v.y));
        tb[q * 4 + 2] = __builtin_bit_cast(unsigned short, __float2bfloat16(v.z));
        tb[q * 4 + 3] = __builtin_bit_cast(unsigned short, __float2bfloat16(v.w));
      }
    }
    *(uint4*)&As[r * 40 + hf * 16] = *(uint4*)&ta[0];
    *(uint4*)&As[r * 40 + hf * 16 + 8] = *(uint4*)&ta[8];
    *(uint4*)&Bs[r * 40 + hf * 16] = *(uint4*)&tb[0];
    *(uint4*)&Bs[r * 40 + hf * 16 + 8] = *(uint4*)&tb[8];
    __syncthreads();
    short8 af[4], bfr[4];
#pragma unroll
    for (int mt = 0; mt < 4; ++mt)
      af[mt] = *(const short8*)&As[(wm + mt * 16 + m16) * 40 + quad * 8];
#pragma unroll
    for (int nt = 0; nt < 4; ++nt)
      bfr[nt] = *(const short8*)&Bs[(wn + nt * 16 + m16) * 40 + quad * 8];
#pragma unroll
    for (int mt = 0; mt < 4; ++mt)
#pragma unroll
      for (int nt = 0; nt < 4; ++nt)
        acc[mt][nt] = __builtin_amdgcn_mfma_f32_16x16x32_bf16(af[mt], bfr[nt],
                                                              acc[mt][nt], 0, 0, 0);
    __syncthreads();
  }
#pragma unroll
  for (int mt = 0; mt < 4; ++mt)
#pragma unroll
    for (int nt = 0; nt < 4; ++nt)
#pragma unroll
      for (int rr = 0; rr < 4; ++rr) {
        int grow = bm * 128 + wm + mt * 16 + quad * 4 + rr;
        int gcol = bn * 128 + wn + nt * 16 + m16;
        float v = acc[mt][nt][rr];
        if (bias) v += bias[gcol];
        if constexpr (std::is_same<TC, float>::value)
          C[(long)grow * ldc + gcol] = v;
        else
          C[(long)grow * ldc + gcol] = __float2half(v);
      }
}

// ---------------------------------------------------------------------------
// GRU recurrence, BATCH-GROUP decomposition: weight replication 64x -> 16x.
// 256 WGs = 16 batch-groups (4 batches) x 16 col-chunks (32 h-cols).
// 512 threads = (col in [0,32)) x (ks in [0,16) k-slices of 32 elements).
// Thread holds 48 weight dwords (3 gates x 16 dw) and dots them against 4
// batches' h (192 fdot2): per-step chip-wide weight traffic is 4x smaller
// than the per-batch baseline whether resident or streamed.
//
// RACE FIX vs failed round 4: strip[] is PARITY DOUBLE-BUFFERED. With one
// barrier per step, a thread that passed poll(t+1) (gated on OTHER WGs) may
// write the strip while a slow wave of its OWN WG still reads step t's data.
// Writing parity (t+1)&1 never touches the buffer being read at parity t&1.
// Re-use of a parity slot at t+2 is safe by the publish-implies-consumed
// chain: publisher emits t+2 only after its WG's BARX(t+1), which requires
// polls of t+1 on ALL pairs, which requires every WG of the batch-group to
// have passed BARX(t) (program order: poll(t) < BARX(t) < publish(t+1)) --
// i.e. all readers of parity t&1 are done. Same induction as the proven
// kernel's part[] double-buffer. Packet protocol/tags/parity and all global
// layouts identical to the proven 4389us kernel.
//
// Per step: 2 packet polls/thread -> strip[ps] (68-dw padded quarters; wave
// reads are same-address broadcast across col-groups + 2-way aliasing = no
// bank conflicts) -> ONE LDS barrier -> dots -> 4-stage shfl_xor butterfly
// over the 16 ks-lanes (gates computed wave-parallel, 4x redundant, no
// divergence) -> publish {h2,tag} + bf16 out store + xg prefetch.
// ---------------------------------------------------------------------------
#define GDOT(g, A)                                                        \
  A = fdot2f(wreg[(g) * 4 + 0][0], H0.x, A);                              \
  A = fdot2f(wreg[(g) * 4 + 0][1], H0.y, A);                              \
  A = fdot2f(wreg[(g) * 4 + 0][2], H0.z, A);                              \
  A = fdot2f(wreg[(g) * 4 + 0][3], H0.w, A);                              \
  A = fdot2f(wreg[(g) * 4 + 1][0], H1.x, A);                              \
  A = fdot2f(wreg[(g) * 4 + 1][1], H1.y, A);                              \
  A = fdot2f(wreg[(g) * 4 + 1][2], H1.z, A);                              \
  A = fdot2f(wreg[(g) * 4 + 1][3], H1.w, A);                              \
  A = fdot2f(wreg[(g) * 4 + 2][0], H2.x, A);                              \
  A = fdot2f(wreg[(g) * 4 + 2][1], H2.y, A);                              \
  A = fdot2f(wreg[(g) * 4 + 2][2], H2.z, A);                              \
  A = fdot2f(wreg[(g) * 4 + 2][3], H2.w, A);                              \
  A = fdot2f(wreg[(g) * 4 + 3][0], H3.x, A);                              \
  A = fdot2f(wreg[(g) * 4 + 3][1], H3.y, A);                              \
  A = fdot2f(wreg[(g) * 4 + 3][2], H3.z, A);                              \
  A = fdot2f(wreg[(g) * 4 + 3][3], H3.w, A);

__global__ __launch_bounds__(512, 1) void gru_rec(
    const uint32_t* __restrict__ wpack, const uint32_t* __restrict__ xgd,
    const float* __restrict__ bhh, uint32_t* __restrict__ hstate,
    uint32_t* __restrict__ outw, uint64_t* __restrict__ pkts,
    float* __restrict__ hid_out,
    int t0, int Tc, int outT, int outT0, int last) {
  const int tid = threadIdx.x;
  const int bgrp = blockIdx.x & 15;  // batch group: batches [4*bgrp, 4*bgrp+4)
  const int wc = blockIdx.x >> 4;    // col chunk: h-cols [32*wc, 32*wc+32)
  const int col = tid >> 4;          // 0..31  (lane = (col&3)*16 + ks)
  const int ks = tid & 15;           // k-slice: k-dwords [16*ks, 16*ks+16)
  const int mybb = ks & 3;           // batch (within group) this lane gates
  const int B = bgrp * 4 + mybb;     // global batch for my gates
  const int colg = wc * 32 + col;    // global h column
  const int p = wc * 16 + (col >> 1);  // global pair index
  const bool pub = ((col & 1) == 0) && ((ks >> 2) == 0);  // publisher lanes

  // h of 4 batches, parity double-buffered, 68-dw padded quarters
  __shared__ uint32_t strip[2][4][272];

  // ---- 48 weight dwords: wreg[g*4+q] = gate g, dwords [ks*16+4q, +4) ----
  u32x4 wreg[12];
  {
    const u32x4* wp =
        (const u32x4*)(wpack + (size_t)(wc * 512 + col * 16 + ks) * 48);
#pragma unroll
    for (int q = 0; q < 12; ++q) wreg[q] = wp[q];
  }

  // ---- persistent per-lane state (col, mybb), replicated across ks>>2 ----
  float hold;
  {
    uint32_t hv = hstate[B * 256 + p];
    __half2 hh = __builtin_bit_cast(__half2, hv);
    hold = (col & 1) ? __half2float(hh.y) : __half2float(hh.x);
  }
  const float bnv = bhh[1024 + colg];
  uint32_t xrw, xzw, xnw;
  {
    size_t base = ((size_t)B * Tc) * 768 + p;
    xrw = xgd[base];
    xzw = xgd[base + 256];
    xnw = xgd[base + 512];
  }

  const int pd = tid & 255;       // packet index within a batch
  const int pq = pd >> 6;         // quarter
  const int po = pd & 63;         // offset in quarter
  const int bb0 = tid >> 8;       // first batch this thread gathers (0 or 1)

  for (int tt = 0; tt < Tc; ++tt) {
    const int t = t0 + tt;
    const int ps = t & 1;
    // ---- gather: 2 packets per thread (batches bb0 and bb0+2) ----
    uint32_t d0v, d1v;
    if (tt == 0) {
      d0v = hstate[(bgrp * 4 + bb0) * 256 + pd];
      d1v = hstate[(bgrp * 4 + bb0 + 2) * 256 + pd];
    } else {
      const uint32_t tg = (uint32_t)t;
      const uint64_t* p0 =
          &pkts[(((size_t)ps) * 64 + bgrp * 4 + bb0) * 256 + pd];
      const uint64_t* p1 = p0 + 2 * 256;
      uint64_t v0, v1;
      do {
        v0 = __hip_atomic_load(p0, __ATOMIC_RELAXED, __HIP_MEMORY_SCOPE_AGENT);
        v1 = __hip_atomic_load(p1, __ATOMIC_RELAXED, __HIP_MEMORY_SCOPE_AGENT);
      } while ((((uint32_t)(v0 >> 32) ^ tg) | ((uint32_t)(v1 >> 32) ^ tg)) != 0u);
      d0v = (uint32_t)v0;
      d1v = (uint32_t)v1;
    }
    strip[ps][bb0][pq * 68 + po] = d0v;
    strip[ps][bb0 + 2][pq * 68 + po] = d1v;
    BARX();  // strips complete (LDS-only drain)

    // ---- dots: 4 batches x 3 gates x 16 dw, weights in wreg ----
    float ar4[4], az4[4], an4[4];
#pragma unroll
    for (int bb = 0; bb < 4; ++bb) {
      const uint32_t* sb = &strip[ps][bb][(ks >> 2) * 68 + (ks & 3) * 16];
      uint4 H0 = *(const uint4*)(sb);
      uint4 H1 = *(const uint4*)(sb + 4);
      uint4 H2 = *(const uint4*)(sb + 8);
      uint4 H3 = *(const uint4*)(sb + 12);
      float a0 = 0.f, a1 = 0.f, a2 = 0.f;
      GDOT(0, a0)
      GDOT(1, a1)
      GDOT(2, a2)
      ar4[bb] = a0;
      az4[bb] = a1;
      an4[bb] = a2;
    }
    // ---- k-reduce: butterfly over the 16 ks-lanes ----
#pragma unroll
    for (int bb = 0; bb < 4; ++bb) {
      float vr = ar4[bb], vz = az4[bb], vn = an4[bb];
      vr += __shfl_xor(vr, 1); vz += __shfl_xor(vz, 1); vn += __shfl_xor(vn, 1);
      vr += __shfl_xor(vr, 2); vz += __shfl_xor(vz, 2); vn += __shfl_xor(vn, 2);
      vr += __shfl_xor(vr, 4); vz += __shfl_xor(vz, 4); vn += __shfl_xor(vn, 4);
      vr += __shfl_xor(vr, 8); vz += __shfl_xor(vz, 8); vn += __shfl_xor(vn, 8);
      ar4[bb] = vr; az4[bb] = vz; an4[bb] = vn;
    }
    // ---- gates for (col, mybb), all lanes (x4 redundancy, no divergence) ----
    float ar = mybb == 0 ? ar4[0] : mybb == 1 ? ar4[1] : mybb == 2 ? ar4[2] : ar4[3];
    float az = mybb == 0 ? az4[0] : mybb == 1 ? az4[1] : mybb == 2 ? az4[2] : az4[3];
    float an = mybb == 0 ? an4[0] : mybb == 1 ? an4[1] : mybb == 2 ? an4[2] : an4[3];
    __half2 xr2 = __builtin_bit_cast(__half2, xrw);
    __half2 xz2 = __builtin_bit_cast(__half2, xzw);
    __half2 xn2 = __builtin_bit_cast(__half2, xnw);
    float xr = (col & 1) ? __half2float(xr2.y) : __half2float(xr2.x);
    float xz = (col & 1) ? __half2float(xz2.y) : __half2float(xz2.x);
    float xn = (col & 1) ? __half2float(xn2.y) : __half2float(xn2.x);
    float r = sigmoid_f(xr + ar);
    float z = sigmoid_f(xz + az);
    float n = tanh_f(xn + r * (an + bnv));
    float h = (1.f - z) * n + z * hold;
    hold = h;
    float hq = __shfl_down(h, 16);  // partner col's h (all lanes active)
    if (pub) {
      uint32_t hd = pack_h2(h, hq);
      uint64_t pk = (uint64_t)hd | ((uint64_t)(uint32_t)(t + 1) << 32);
      __hip_atomic_store(&pkts[(((size_t)((t + 1) & 1)) * 64 + B) * 256 + p],
                         pk, __ATOMIC_RELAXED, __HIP_MEMORY_SCOPE_AGENT);
      outw[((size_t)B * outT + outT0 + tt) * 256 + p] = pack_bf2(h, hq);
    }
    // prefetch next step's xg
    if (tt + 1 < Tc) {
      size_t base = ((size_t)B * Tc + tt + 1) * 768 + p;
      xrw = xgd[base];
      xzw = xgd[base + 256];
      xnw = xgd[base + 512];
    }
  }

  // carry h to next dispatch / final hidden output
  {
    float hq2 = __shfl_down(hold, 16);
    if (pub) {
      hstate[B * 256 + p] = pack_h2(hold, hq2);
      if (last) {
        float2 hv = make_float2(hold, hq2);
        *(float2*)&hid_out[B * 512 + 2 * p] = hv;
      }
    }
  }
}

// ---------------------------------------------------------------------------
extern "C" void kernel_launch(void* const* d_in, const int* in_sizes, int n_in,
                              void* d_out, int out_size, void* d_ws, size_t ws_size,
                              hipStream_t stream) {
  const float* x = (const float*)d_in[0];
  const float* W_ih0 = (const float*)d_in[1];
  const float* W_hh0 = (const float*)d_in[2];
  const float* b_ih0 = (const float*)d_in[3];
  const float* b_hh0 = (const float*)d_in[4];
  const float* W_ih1 = (const float*)d_in[5];
  const float* W_hh1 = (const float*)d_in[6];
  const float* b_ih1 = (const float*)d_in[7];
  const float* b_hh1 = (const float*)d_in[8];
  const float* fc_w = (const float*)d_in[9];
  const float* fc_b = (const float*)d_in[10];
  float* out = (float*)d_out;

  char* p = (char*)d_ws;
  size_t off = 0;
  auto alloc = [&](size_t bytes) -> void* {
    void* r = p + off;
    off = (off + bytes + 255) & ~(size_t)255;
    return r;
  };
  uint32_t* wpack = (uint32_t*)alloc((size_t)786432 * 4);
  float* biasv = (float*)alloc((size_t)3072 * 4);
  uint32_t* hstate = (uint32_t*)alloc((size_t)32768 * 4);
  // packets: 2 layers x 2 slots x 64 batch x 256 pairs x u64
  uint64_t* pkts = (uint64_t*)alloc((size_t)2 * 2 * 64 * 256 * 8);
  __hip_bfloat16* out1 = (__hip_bfloat16*)alloc((size_t)B_ * T_ * H_ * 2);

  int Tc = 1024;
  while (Tc > 64) {
    size_t need = (size_t)B_ * Tc * H_ * 2 + (size_t)B_ * Tc * G3_ * 2 + 1024;
    if (off + need <= ws_size) break;
    Tc >>= 1;
  }
  __hip_bfloat16* out0c = (__hip_bfloat16*)alloc((size_t)B_ * Tc * H_ * 2);
  __half* xg = (__half*)alloc((size_t)B_ * Tc * G3_ * 2);
  int tcs = __builtin_ctz(Tc);

  init_kernel<<<3212, 256, 0, stream>>>(W_hh0, W_hh1, b_ih0, b_hh0, b_ih1, b_hh1,
                                        wpack, biasv, hstate);

  for (int t0 = 0; t0 < 1024; t0 += Tc) {
    const int M = B_ * Tc;
    const int last = (t0 + Tc) == 1024;
    // ---- layer 0 ----
    {
      dim3 gg(M / 128, G3_ / 128);
      gemm_bt<float, __half><<<gg, 256, 0, stream>>>(x, W_ih0, biasv, xg, I_, I_,
                                                     G3_, tcs, t0, 1024);
      gru_rec<<<256, 512, 0, stream>>>(wpack, (const uint32_t*)xg, b_hh0, hstate,
                                       (uint32_t*)out0c, pkts,
                                       out + 16777216, t0, Tc, Tc, 0, last);
    }
    // ---- layer 1 ----
    {
      dim3 gg(M / 128, G3_ / 128);
      gemm_bt<__hip_bfloat16, __half><<<gg, 256, 0, stream>>>(
          out0c, W_ih1, biasv + 1536, xg, H_, H_, G3_, tcs, 0, Tc);
      gru_rec<<<256, 512, 0, stream>>>(wpack + 393216, (const uint32_t*)xg, b_hh1,
                                       hstate + 16384, (uint32_t*)out1,
                                       pkts + 32768,
                                       out + 16777216 + 32768, t0, Tc, 1024, t0, last);
    }
  }
  // FC: [65536,512] x fc_w[256,512]^T + fc_b -> d_out fp32
  dim3 gf(65536 / 128, O_ / 128);
  gemm_bt<__hip_bfloat16, float><<<gf, 256, 0, stream>>>(out1, fc_w, fc_b, out,
                                                         H_, H_, O_, 10, 0, 1024);
}

// Round 6
// 7081.947 us; speedup vs baseline: 1.4505x; 1.4505x over previous
//
#include <hip/hip_runtime.h>
#include <hip/hip_bf16.h>
#include <hip/hip_fp16.h>
#include <stdint.h>
#include <type_traits>

// Problem constants
#define B_ 64
#define T_ 1024
#define I_ 256
#define H_ 512
#define G3_ 1536
#define O_ 256

typedef __attribute__((ext_vector_type(4))) float floatx4;
typedef __attribute__((ext_vector_type(8))) short short8;
typedef __attribute__((ext_vector_type(2))) _Float16 half2v;
typedef __attribute__((ext_vector_type(4))) unsigned int u32x4;

// Raw workgroup barrier: drains LDS only, NOT vmcnt. Keeps HBM/LLC ops
// (out stores, xg prefetch, packet stores) off the per-step critical path.
#define BARX() __asm__ volatile("s_waitcnt lgkmcnt(0)\n\ts_barrier" ::: "memory")

static __device__ __forceinline__ float fdot2f(uint32_t a, uint32_t b, float c) {
#if __has_builtin(__builtin_amdgcn_fdot2)
  return __builtin_amdgcn_fdot2(__builtin_bit_cast(half2v, a),
                                __builtin_bit_cast(half2v, b), c, false);
#else
  __half2 ha = __builtin_bit_cast(__half2, a);
  __half2 hb = __builtin_bit_cast(__half2, b);
  float2 fa = __half22float2(ha), fb = __half22float2(hb);
  return c + fa.x * fb.x + fa.y * fb.y;
#endif
}

static __device__ __forceinline__ float sigmoid_f(float x) {
  float e = __expf(-fabsf(x));
  float a = 1.f / (1.f + e);
  return x >= 0.f ? a : 1.f - a;
}
static __device__ __forceinline__ float tanh_f(float x) {
  float e = __expf(-2.f * fabsf(x));
  float a = (1.f - e) / (1.f + e);
  return x >= 0.f ? a : -a;
}
static __device__ __forceinline__ uint32_t pack_h2(float a, float b) {
  return (uint32_t)__half_as_ushort(__float2half(a)) |
         ((uint32_t)__half_as_ushort(__float2half(b)) << 16);
}
static __device__ __forceinline__ uint32_t pack_bf2(float a, float b) {
  return (uint32_t)__builtin_bit_cast(unsigned short, __float2bfloat16(a)) |
         ((uint32_t)__builtin_bit_cast(unsigned short, __float2bfloat16(b)) << 16);
}

// ---------------------------------------------------------------------------
// init: pack W_hh -> fp16 per-thread CONTIGUOUS 96-dword blocks (so the
// in-loop streaming loads are global_load_dwordx4), combined biases, zero h.
// wpack dword index: ((c*8 + s)*64 + j)*96 + g*32 + dw  (+ l*393216)
//   thread (c,s,j): for gate g, fp16 pair {W[g*512+c*64+j][(s*32+dw)*2],
//   W[..][(s*32+dw)*2+1]}  — row c*64+j, k-slice s (32 dwords).
// Packets need NO init: 0xAAAAAAAA poison never equals a tag (tags <= 1025).
// ---------------------------------------------------------------------------
__global__ void init_kernel(const float* __restrict__ Whh0, const float* __restrict__ Whh1,
                            const float* __restrict__ bih0, const float* __restrict__ bhh0,
                            const float* __restrict__ bih1, const float* __restrict__ bhh1,
                            uint32_t* __restrict__ wpack, float* __restrict__ biasv,
                            uint32_t* __restrict__ hstate) {
  int idx = blockIdx.x * 256 + threadIdx.x;
  if (idx < 786432) {
    int l = idx / 393216, r = idx % 393216;
    int i = r % 96;
    int tb = r / 96;         // (c*8 + s)*64 + j
    int j = tb & 63;
    int s = (tb >> 6) & 7;
    int c = tb >> 9;
    int g = i >> 5, dw = i & 31;
    const float* W = l ? Whh1 : Whh0;
    int row = g * 512 + c * 64 + j;
    int k = (s * 32 + dw) * 2;
    uint32_t lo = __half_as_ushort(__float2half(W[(size_t)row * 512 + k]));
    uint32_t hi = __half_as_ushort(__float2half(W[(size_t)row * 512 + k + 1]));
    wpack[idx] = lo | (hi << 16);
  }
  int i2 = idx - 786432;
  if (i2 >= 0 && i2 < 3072) {
    int l = i2 / 1536, n = i2 % 1536;
    const float* bi = l ? bih1 : bih0;
    const float* bh = l ? bhh1 : bhh0;
    biasv[i2] = bi[n] + (n < 1024 ? bh[n] : 0.f);
  }
  int i3 = idx - (786432 + 3072);
  if (i3 >= 0 && i3 < 32768) hstate[i3] = 0u;
}

// ---------------------------------------------------------------------------
// GEMM: C[M,N] = A[M,K] * Bw[N,K]^T + bias, bf16 MFMA 16x16x32. (unchanged)
// ---------------------------------------------------------------------------
template <typename TA, typename TC>
__global__ __launch_bounds__(256, 2) void gemm_bt(
    const TA* __restrict__ A, const float* __restrict__ Bw,
    const float* __restrict__ bias, TC* __restrict__ C,
    int K, int lda, int ldc, int tcshift, int t0, int Ttot) {
  __shared__ unsigned short As[128 * 40];
  __shared__ unsigned short Bs[128 * 40];
  const int tid = threadIdx.x;
  const int bm = blockIdx.x, bn = blockIdx.y;
  const int r = tid >> 1, hf = tid & 1;

  const int m = bm * 128 + r;
  const long arow = (long)(m >> tcshift) * Ttot + t0 + (m & ((1 << tcshift) - 1));
  const TA* ap = A + arow * (long)lda + hf * 16;
  const int n = bn * 128 + r;
  const float* bp = Bw + (long)n * K + hf * 16;

  const int wid = tid >> 6, lane = tid & 63;
  const int wm = (wid >> 1) * 64, wn = (wid & 1) * 64;
  const int m16 = lane & 15, quad = lane >> 4;

  floatx4 acc[4][4];
#pragma unroll
  for (int i = 0; i < 4; ++i)
#pragma unroll
    for (int j = 0; j < 4; ++j) acc[i][j] = 0.f;

  for (int k0 = 0; k0 < K; k0 += 32) {
    unsigned short ta[16], tb[16];
    if constexpr (std::is_same<TA, float>::value) {
      const float4* p = (const float4*)(ap + k0);
#pragma unroll
      for (int q = 0; q < 4; ++q) {
        float4 v = p[q];
        ta[q * 4 + 0] = __builtin_bit_cast(unsigned short, __float2bfloat16(v.x));
        ta[q * 4 + 1] = __builtin_bit_cast(unsigned short, __float2bfloat16(v.y));
        ta[q * 4 + 2] = __builtin_bit_cast(unsigned short, __float2bfloat16(v.z));
        ta[q * 4 + 3] = __builtin_bit_cast(unsigned short, __float2bfloat16(v.w));
      }
    } else {
      const uint4* p = (const uint4*)(ap + k0);
      *(uint4*)&ta[0] = p[0];
      *(uint4*)&ta[8] = p[1];
    }
    {
      const float4* p = (const float4*)(bp + k0);
#pragma unroll
      for (int q = 0; q < 4; ++q) {
        float4 v = p[q];
        tb[q * 4 + 0] = __builtin_bit_cast(unsigned short, __float2bfloat16(v.x));
        tb[q * 4 + 1] = __builtin_bit_cast(unsigned short, __float2bfloat16(v.y));
        tb[q * 4 + 2] = __builtin_bit_cast(unsigned short, __float2bfloat16(v.z));
        tb[q * 4 + 3] = __builtin_bit_cast(unsigned short, __float2bfloat16(v.w));
      }
    }
    *(uint4*)&As[r * 40 + hf * 16] = *(uint4*)&ta[0];
    *(uint4*)&As[r * 40 + hf * 16 + 8] = *(uint4*)&ta[8];
    *(uint4*)&Bs[r * 40 + hf * 16] = *(uint4*)&tb[0];
    *(uint4*)&Bs[r * 40 + hf * 16 + 8] = *(uint4*)&tb[8];
    __syncthreads();
    short8 af[4], bfr[4];
#pragma unroll
    for (int mt = 0; mt < 4; ++mt)
      af[mt] = *(const short8*)&As[(wm + mt * 16 + m16) * 40 + quad * 8];
#pragma unroll
    for (int nt = 0; nt < 4; ++nt)
      bfr[nt] = *(const short8*)&Bs[(wn + nt * 16 + m16) * 40 + quad * 8];
#pragma unroll
    for (int mt = 0; mt < 4; ++mt)
#pragma unroll
      for (int nt = 0; nt < 4; ++nt)
        acc[mt][nt] = __builtin_amdgcn_mfma_f32_16x16x32_bf16(af[mt], bfr[nt],
                                                              acc[mt][nt], 0, 0, 0);
    __syncthreads();
  }
#pragma unroll
  for (int mt = 0; mt < 4; ++mt)
#pragma unroll
    for (int nt = 0; nt < 4; ++nt)
#pragma unroll
      for (int rr = 0; rr < 4; ++rr) {
        int grow = bm * 128 + wm + mt * 16 + quad * 4 + rr;
        int gcol = bn * 128 + wn + nt * 16 + m16;
        float v = acc[mt][nt][rr];
        if (bias) v += bias[gcol];
        if constexpr (std::is_same<TC, float>::value)
          C[(long)grow * ldc + gcol] = v;
        else
          C[(long)grow * ldc + gcol] = __float2half(v);
      }
}

// ---------------------------------------------------------------------------
// GRU recurrence — baseline structure, 8 row-chunk WGs per batch.
// 512 WGs: c = blk&7 (64-row chunk), b = blk>>3 (batch). This mapping puts
// block k and k+256 (the co-resident pair on a CU) on the SAME chunk c ->
// identical weight stream -> L1 reuse (fresh weight bytes/CU/step 786->196KB).
// 512 threads: wave s = tid>>6 = k-slice (32 dwords), j = tid&63 = row.
// Per thread per step: 24 x global_load_dwordx4 weight stream (contiguous
// pack; compiler keeps them in-loop which is what we want) + 96 fdot2
// (vs baseline 192 scalar loads + 192 fdot2).
// Per step: wave s polls its 32 packets (2 lanes/packet, benign dup) ->
// wave-local LDS strip (same-wave lgkm ordering, single-buffered: only the
// owning wave reads it, and it re-writes only after its own next poll) ->
// dots -> partials to parity-double-buffered part[ps] -> BARX (the ONE
// barrier) -> wave0: reduce 8 slices, gates (1 h per lane), publish {h2,tag}
// packets (even lanes, pair via shfl), bf16 out store, xg prefetch.
// part[] parity reuse at t+2 is safe by the publish-implies-consumed
// induction (identical to the proven kernel: every WG of batch b has a wave
// polling every chunk-WG of b, so publish(t+2) transitively requires all
// readers of parity t&1 to have passed BARX(t+1)).
// Packet protocol/tags/parity and all global layouts identical to the proven
// 4389us kernel.
// ---------------------------------------------------------------------------
__global__ __launch_bounds__(512, 2) void gru_rec(
    const uint32_t* __restrict__ wpack, const uint32_t* __restrict__ xgd,
    const float* __restrict__ bhh, uint32_t* __restrict__ hstate,
    uint32_t* __restrict__ outw, uint64_t* __restrict__ pkts,
    float* __restrict__ hid_out,
    int t0, int Tc, int outT, int outT0, int last) {
  const int tid = threadIdx.x;
  const int s = tid >> 6;         // wave = k-slice (32 dwords of h)
  const int j = tid & 63;         // row within this WG's 64-row chunk
  const int c = blockIdx.x & 7;   // row chunk
  const int b = blockIdx.x >> 3;  // batch
  const int m32 = j & 31;         // packet index within slice (2 lanes/packet)
  const int p = c * 32 + (j >> 1);  // global h-pair index (wave0 gates role)

  __shared__ uint32_t hbw[8][32];      // per-slice h strips (fp16x2)
  __shared__ float part[2][3][64][9];  // [parity][gate][row][slice(+pad)]

  const uint32_t* wp = wpack + ((size_t)(c * 8 + s) * 64 + j) * 96;

  // wave0 persistent state: ONE h per lane (col = c*64 + j)
  float hold = 0.f, bnv = 0.f;
  uint32_t xrw = 0, xzw = 0, xnw = 0;
  if (s == 0) {
    uint32_t hv = hstate[b * 256 + p];
    __half2 hh = __builtin_bit_cast(__half2, hv);
    hold = (j & 1) ? __half2float(hh.y) : __half2float(hh.x);
    bnv = bhh[1024 + c * 64 + j];
    size_t base = ((size_t)b * Tc) * 768 + p;
    xrw = xgd[base];
    xzw = xgd[base + 256];
    xnw = xgd[base + 512];
  }

  for (int tt = 0; tt < Tc; ++tt) {
    const int t = t0 + tt;
    // ---- acquire this wave's h slice: 32 packets, 2 lanes each ----
    uint32_t hp;
    if (tt == 0) {
      hp = hstate[b * 256 + s * 32 + m32];  // seeded by prev dispatch
    } else {
      const uint64_t* pp = &pkts[(((size_t)(t & 1)) * 64 + b) * 256 + s * 32 + m32];
      uint64_t v;
      do {
        v = __hip_atomic_load(pp, __ATOMIC_RELAXED, __HIP_MEMORY_SCOPE_AGENT);
      } while ((uint32_t)(v >> 32) != (uint32_t)t);
      hp = (uint32_t)v;
    }
    hbw[s][m32] = hp;  // same-wave lgkm ordering; dup lane writes same value
    // ---- dots: 3 gates x 32 dw, weights streamed as dwordx4 ----
    float ar = 0.f, az = 0.f, an = 0.f;
#pragma unroll
    for (int d4 = 0; d4 < 8; ++d4) {
      uint4 H = *((const uint4*)&hbw[s][0] + d4);  // broadcast read
      u32x4 wr = *(const u32x4*)(wp + d4 * 4);
      u32x4 wz = *(const u32x4*)(wp + 32 + d4 * 4);
      u32x4 wn = *(const u32x4*)(wp + 64 + d4 * 4);
      ar = fdot2f(wr[0], H.x, ar); az = fdot2f(wz[0], H.x, az); an = fdot2f(wn[0], H.x, an);
      ar = fdot2f(wr[1], H.y, ar); az = fdot2f(wz[1], H.y, az); an = fdot2f(wn[1], H.y, an);
      ar = fdot2f(wr[2], H.z, ar); az = fdot2f(wz[2], H.z, az); an = fdot2f(wn[2], H.z, an);
      ar = fdot2f(wr[3], H.w, ar); az = fdot2f(wz[3], H.w, az); an = fdot2f(wn[3], H.w, an);
    }
    const int ps = t & 1;
    part[ps][0][j][s] = ar;   // banks (9j+s)%32: 2-way max = free
    part[ps][1][j][s] = az;
    part[ps][2][j][s] = an;
    BARX();  // THE one barrier: partials slot ps complete

    if (s == 0) {
      float hr = 0.f, hz = 0.f, hn = 0.f;
#pragma unroll
      for (int ss = 0; ss < 8; ++ss) {
        hr += part[ps][0][j][ss];
        hz += part[ps][1][j][ss];
        hn += part[ps][2][j][ss];
      }
      __half2 xr2 = __builtin_bit_cast(__half2, xrw);
      __half2 xz2 = __builtin_bit_cast(__half2, xzw);
      __half2 xn2 = __builtin_bit_cast(__half2, xnw);
      float xr = (j & 1) ? __half2float(xr2.y) : __half2float(xr2.x);
      float xz = (j & 1) ? __half2float(xz2.y) : __half2float(xz2.x);
      float xn = (j & 1) ? __half2float(xn2.y) : __half2float(xn2.x);
      float r = sigmoid_f(xr + hr);
      float z = sigmoid_f(xz + hz);
      float n = tanh_f(xn + r * (hn + bnv));
      float h = (1.f - z) * n + z * hold;
      hold = h;
      float hq = __shfl_down(h, 1);  // partner row's h (wave-uniform branch)
      if ((j & 1) == 0) {
        uint32_t hd = pack_h2(h, hq);
        // publish: ONE 8B packet {data, tag}; no drain/fence needed
        uint64_t pk = (uint64_t)hd | ((uint64_t)(uint32_t)(t + 1) << 32);
        __hip_atomic_store(&pkts[(((size_t)((t + 1) & 1)) * 64 + b) * 256 + p],
                           pk, __ATOMIC_RELAXED, __HIP_MEMORY_SCOPE_AGENT);
        // fire-and-forget out store (bf16 pair)
        outw[((size_t)b * outT + outT0 + tt) * 256 + p] = pack_bf2(h, hq);
      }
      // prefetch next step's xg (consumed at next gates; ~full step to cover)
      if (tt + 1 < Tc) {
        size_t base = ((size_t)b * Tc + tt + 1) * 768 + p;
        xrw = xgd[base];
        xzw = xgd[base + 256];
        xnw = xgd[base + 512];
      }
    }
  }

  if (s == 0) {
    float hq2 = __shfl_down(hold, 1);
    if ((j & 1) == 0) {
      hstate[b * 256 + p] = pack_h2(hold, hq2);
      if (last) {
        float2 hv = make_float2(hold, hq2);
        *(float2*)&hid_out[b * 512 + 2 * p] = hv;
      }
    }
  }
}

// ---------------------------------------------------------------------------
extern "C" void kernel_launch(void* const* d_in, const int* in_sizes, int n_in,
                              void* d_out, int out_size, void* d_ws, size_t ws_size,
                              hipStream_t stream) {
  const float* x = (const float*)d_in[0];
  const float* W_ih0 = (const float*)d_in[1];
  const float* W_hh0 = (const float*)d_in[2];
  const float* b_ih0 = (const float*)d_in[3];
  const float* b_hh0 = (const float*)d_in[4];
  const float* W_ih1 = (const float*)d_in[5];
  const float* W_hh1 = (const float*)d_in[6];
  const float* b_ih1 = (const float*)d_in[7];
  const float* b_hh1 = (const float*)d_in[8];
  const float* fc_w = (const float*)d_in[9];
  const float* fc_b = (const float*)d_in[10];
  float* out = (float*)d_out;

  char* p = (char*)d_ws;
  size_t off = 0;
  auto alloc = [&](size_t bytes) -> void* {
    void* r = p + off;
    off = (off + bytes + 255) & ~(size_t)255;
    return r;
  };
  uint32_t* wpack = (uint32_t*)alloc((size_t)786432 * 4);
  float* biasv = (float*)alloc((size_t)3072 * 4);
  uint32_t* hstate = (uint32_t*)alloc((size_t)32768 * 4);
  // packets: 2 layers x 2 slots x 64 batch x 256 pairs x u64
  uint64_t* pkts = (uint64_t*)alloc((size_t)2 * 2 * 64 * 256 * 8);
  __hip_bfloat16* out1 = (__hip_bfloat16*)alloc((size_t)B_ * T_ * H_ * 2);

  int Tc = 1024;
  while (Tc > 64) {
    size_t need = (size_t)B_ * Tc * H_ * 2 + (size_t)B_ * Tc * G3_ * 2 + 1024;
    if (off + need <= ws_size) break;
    Tc >>= 1;
  }
  __hip_bfloat16* out0c = (__hip_bfloat16*)alloc((size_t)B_ * Tc * H_ * 2);
  __half* xg = (__half*)alloc((size_t)B_ * Tc * G3_ * 2);
  int tcs = __builtin_ctz(Tc);

  init_kernel<<<3212, 256, 0, stream>>>(W_hh0, W_hh1, b_ih0, b_hh0, b_ih1, b_hh1,
                                        wpack, biasv, hstate);

  for (int t0 = 0; t0 < 1024; t0 += Tc) {
    const int M = B_ * Tc;
    const int last = (t0 + Tc) == 1024;
    // ---- layer 0 ----
    {
      dim3 gg(M / 128, G3_ / 128);
      gemm_bt<float, __half><<<gg, 256, 0, stream>>>(x, W_ih0, biasv, xg, I_, I_,
                                                     G3_, tcs, t0, 1024);
      gru_rec<<<512, 512, 0, stream>>>(wpack, (const uint32_t*)xg, b_hh0, hstate,
                                       (uint32_t*)out0c, pkts,
                                       out + 16777216, t0, Tc, Tc, 0, last);
    }
    // ---- layer 1 ----
    {
      dim3 gg(M / 128, G3_ / 128);
      gemm_bt<__hip_bfloat16, __half><<<gg, 256, 0, stream>>>(
          out0c, W_ih1, biasv + 1536, xg, H_, H_, G3_, tcs, 0, Tc);
      gru_rec<<<512, 512, 0, stream>>>(wpack + 393216, (const uint32_t*)xg, b_hh1,
                                       hstate + 16384, (uint32_t*)out1,
                                       pkts + 32768,
                                       out + 16777216 + 32768, t0, Tc, 1024, t0, last);
    }
  }
  // FC: [65536,512] x fc_w[256,512]^T + fc_b -> d_out fp32
  dim3 gf(65536 / 128, O_ / 128);
  gemm_bt<__hip_bfloat16, float><<<gf, 256, 0, stream>>>(out1, fc_w, fc_b, out,
                                                         H_, H_, O_, 10, 0, 1024);
}